// Round 7
// baseline (163.904 us; speedup 1.0000x reference)
//
#include <hip/hip_runtime.h>

// CharBiLSTMEmbedder: N=32768 words, T=20, E=H=50, V=200, out [N,100] fp32.
//
// Round-13: RESUBMIT of round-12 (bench infra failed: "container failed
// twice"; static re-audit found no hang/fault path - barriers block-uniform,
// bounds/alignment verified, tile-6 dup is a benign same-value write).
//
// Structure: block = 128 thr = 2 waves = ONE 16-word group. wave0 tiles 0-6,
// wave1 tiles 6-12 (tile 6 duplicated: identical values, benign).
// A-frags (7 tiles) in registers; h dbuf 4KB LDS; 1 barrier/step between
// 2 waves only; ~8 blocks/CU co-resident -> decorrelated stalls, LPT
// backfill over 4096 small blocks. launch_bounds(128,4): cap 128 > need.
// NOTE: occupancy metric will read ~50% (16/32 waves, VGPR-capped) - expected.
// Carried: bf16 G from L2 (shift/and unpack), exp2-domain gates, counting
// sort, k_prep with LDS-staged Wih (bf16 out), 3 plain launches.

#define TT    20
#define HH    50
#define VV    200
#define TILES 13        // 13*16 = 208 rows >= 200
#define GSTR  212       // G row stride in shorts (53 units * 4 gates)
#define GSH   (VV * GSTR)        // 42400 shorts per dir
#define WSH   (TILES * 16 * 64)  // 13312 shorts per dir
#define NW    32768
#define NB_G  50        // 2 dirs * 25 blocks of 8 emb rows
#define NB_W  104       // ceil(2*WSH/256)
#define NB_H  128       // 128*256 = 32768 words
#define NBLK  4096      // 2 dirs * 2048 groups of 16 words

#define N2LOG2E (-1.4426950408889634f)
#define P2LOG2E 2.8853900817779268f

typedef __attribute__((ext_vector_type(8))) short bf16x8;
typedef __attribute__((ext_vector_type(4))) float f32x4;

__device__ __forceinline__ float frcp(float x) { return __builtin_amdgcn_rcpf(x); }
#if __has_builtin(__builtin_amdgcn_exp2f)
__device__ __forceinline__ float fexp2(float x) { return __builtin_amdgcn_exp2f(x); }
#else
__device__ __forceinline__ float fexp2(float x) { return exp2f(x); }
#endif

__device__ __forceinline__ short f2bf(float x) {  // RNE fp32 -> bf16
    unsigned b = __builtin_bit_cast(unsigned, x);
    unsigned r = (b + 0x7FFFu + ((b >> 16) & 1u)) >> 16;
    return (short)r;
}
__device__ __forceinline__ float bfhi(unsigned w) {   // high bf16 of dword
    return __builtin_bit_cast(float, w & 0xFFFF0000u);
}
__device__ __forceinline__ float bflo(unsigned w) {   // low bf16 of dword
    return __builtin_bit_cast(float, w << 16);
}

// One kernel, three jobs by block range:
//  [0,NB_G): Gimg[d][v*GSTR+u*4+g] = bf16(sc_g*(emb'[v].W_ih[g*50+u]+b_ih+b_hh))
//            (Wih staged in LDS with sc folded; emb reads wave-uniform)
//  [NB_G,NB_G+NB_W): Wimg = MFMA A-operand image of sc_g*Whh (bf16, k-swizzled)
//  [NB_G+NB_W, +NB_H): cnt[block][21] = length histogram of 256 words
//  sc_g = -log2e for i,f,o rows; +2log2e for g rows (exp2-domain gates).
__global__ void k_prep(const float* __restrict__ emb,
                       const float* __restrict__ Wih_f, const float* __restrict__ bih_f,
                       const float* __restrict__ bhh_f,
                       const float* __restrict__ Wih_b, const float* __restrict__ bih_b,
                       const float* __restrict__ bhh_b,
                       const float* __restrict__ Whh_f, const float* __restrict__ Whh_b,
                       const int* __restrict__ lens,
                       short* __restrict__ Gimg, short* __restrict__ Wimg,
                       int* __restrict__ cnt) {
    int blk = blockIdx.x;
    int tid = threadIdx.x;
    __shared__ float Wl[4 * HH * HH];    // 200x50 f32, pre-scaled (40000 B)
    __shared__ float bs[4 * HH];         // (b_ih+b_hh)*sc

    if (blk < NB_G) {
        int d = blk / 25;
        int vbase = (blk % 25) * 8;
        const float* Wih = d ? Wih_b : Wih_f;
        const float* bih = d ? bih_b : bih_f;
        const float* bhh = d ? bhh_b : bhh_f;
        for (int i = tid; i < 4 * HH * HH; i += 256) {
            int r = i / HH;
            float sc = (r / HH == 2) ? P2LOG2E : N2LOG2E;
            Wl[i] = Wih[i] * sc;
        }
        if (tid < 4 * HH) {
            float sc = (tid / HH == 2) ? P2LOG2E : N2LOG2E;
            bs[tid] = (bih[tid] + bhh[tid]) * sc;
        }
        __syncthreads();
        int r = tid;                      // gate-row 0..199
        if (r < 4 * HH) {
            int g = r / HH, u = r % HH;
            #pragma unroll
            for (int vv = 0; vv < 8; ++vv) {
                int v = vbase + vv;
                float s = bs[r];
                if (v != 0) {             // PAD row of emb is zero
                    #pragma unroll 10
                    for (int e = 0; e < HH; ++e)
                        s = fmaf(emb[v * HH + e], Wl[r * HH + e], s);
                }
                Gimg[d * GSH + v * GSTR + u * 4 + g] = f2bf(s);
            }
        } else {                          // zero pad units u=50..52 (12 shorts/v)
            for (int k = r - 4 * HH; k < 8 * 12; k += 56) {
                int v = vbase + k / 12;
                Gimg[d * GSH + v * GSTR + 4 * HH + (k % 12)] = 0;
            }
        }
    } else if (blk < NB_G + NB_W) {
        int idx = (blk - NB_G) * 256 + tid;
        if (idx >= 2 * WSH) return;
        int d = idx / WSH;
        int e = idx % WSH;
        int t = e >> 10, m = (e >> 6) & 15, k = e & 63;
        int u = 4 * t + (m >> 2), g = m & 3;
        const float* Whh = d ? Whh_b : Whh_f;
        float sc = (g == 2) ? P2LOG2E : N2LOG2E;
        float val = (k < HH && u < HH) ? Whh[(g * HH + u) * HH + k] * sc : 0.0f;
        int ksw = (k & 7) | (((k >> 3) ^ (m & 7)) << 3);
        Wimg[d * WSH + (e & ~63) + ksw] = f2bf(val);
    } else {
        int hb = blk - NB_G - NB_W;      // 0..127
        __shared__ int hcnt[21];
        if (tid < 21) hcnt[tid] = 0;
        __syncthreads();
        atomicAdd(&hcnt[lens[hb * 256 + tid]], 1);
        __syncthreads();
        if (tid < 21) cnt[hb * 21 + tid] = hcnt[tid];
    }
}

// Merged scan+scatter: every block stages the 128x21 histogram into LDS,
// computes its own bucket offsets (buckets ordered L=20..0, LPT), scatters
// its 256 words.
__global__ void k_scat(const int* __restrict__ lens, const int* __restrict__ cnt,
                       int* __restrict__ perm) {
    __shared__ int lcnt[NB_H * 21];     // 10752 B
    __shared__ int part[8][21];
    __shared__ int tot[21];
    __shared__ int cur[21];
    int b = blockIdx.x, t = threadIdx.x;
    for (int i = t; i < NB_H * 21; i += 256) lcnt[i] = cnt[i];
    __syncthreads();
    if (t < 168) {
        int L = t % 21, c = t / 21;
        int s = 0;
        for (int bb = c * 16; bb < c * 16 + 16; ++bb) s += lcnt[bb * 21 + L];
        part[c][L] = s;
    }
    __syncthreads();
    if (t < 21) {
        int a = 0;
        #pragma unroll
        for (int c = 0; c < 8; ++c) a += part[c][t];
        tot[t] = a;
    }
    __syncthreads();
    if (t < 21) {
        int a = 0;
        for (int L2 = 20; L2 > t; --L2) a += tot[L2];   // start of bucket t
        for (int bb = 0; bb < b; ++bb) a += lcnt[bb * 21 + t];
        cur[t] = a;
    }
    __syncthreads();
    int i = b * 256 + t;
    int pos = atomicAdd(&cur[lens[i]], 1);
    perm[pos] = i;
}

// Block = 2 waves x one 16-word group. wave0: tiles 0-6, wave1: tiles 6-12.
// A-frags in registers (7x2 bf16x8); h double-buffer in LDS; 1 barrier/step.
__launch_bounds__(128, 4)
__global__ void k_lstm(const int* __restrict__ chars, const int* __restrict__ lens,
                       const int* __restrict__ perm,
                       const short* __restrict__ Gimg, const short* __restrict__ Wimg,
                       float* __restrict__ out) {
    __shared__ __align__(16) short hs[2][1024];    // 4096 B
    __shared__ unsigned short cs[16 * TT];         // 640 B (char*GSTR offsets)

    int gb   = blockIdx.x;             // 0..4095, LPT (longest groups first)
    int d    = gb & 1;
    int grp  = gb >> 1;                // 0..2047
    int tid  = threadIdx.x;            // 0..127
    int lane = tid & 63;
    int wv   = __builtin_amdgcn_readfirstlane(tid >> 6);   // 0..1
    int quad = lane >> 4;
    int n    = lane & 15;
    int x7   = n & 7;
    int slotbase = grp * 16;

    {   // zero both h buffers (4096 B = 256 int4, 2 per thread)
        int4 z = {0, 0, 0, 0};
        int4* hz = (int4*)&hs[0][0];
        hz[tid] = z;
        hz[tid + 128] = z;
    }
    for (int i = tid; i < 16 * TT; i += 128) {     // chars as v*GSTR offsets
        int w = perm[slotbase + i / TT];
        cs[i] = (unsigned short)(chars[w * TT + i % TT] * GSTR);
    }

    int word = perm[slotbase + n];
    int L = lens[word];
    int mL = L;                         // group max length
    #pragma unroll
    for (int off = 8; off; off >>= 1) {
        int t2 = __shfl_xor(mL, off);
        mL = mL > t2 ? mL : t2;
    }
    mL = __builtin_amdgcn_readfirstlane(mL);

    int pa0 = quad ^ x7;               // swizzled k-group, k 0..31
    int pa1 = (quad + 4) ^ x7;         // k 32..63
    int tbase = wv * 6;                // wave0: 0..6, wave1: 6..12
    int u0 = 4 * tbase + quad;

    // A fragments (Whh image): 7 tiles, one-time read from L2
    const short* Wd = Wimg + d * WSH;
    bf16x8 A0[7], A1[7];
    #pragma unroll
    for (int tt = 0; tt < 7; ++tt) {
        int t = tbase + tt;
        A0[tt] = *(const bf16x8*)(Wd + (t * 16 + n) * 64 + pa0 * 8);
        A1[tt] = *(const bf16x8*)(Wd + (t * 16 + n) * 64 + pa1 * 8);
    }
    // per-tile h-LDS index (loop-invariant)
    int hidx[7];
    #pragma unroll
    for (int tt = 0; tt < 7; ++tt) {
        int uu = u0 + 4 * tt;
        hidx[tt] = n * 64 + (((uu >> 3) ^ x7) << 3) + (uu & 7);
    }

    const short* Gq = Gimg + d * GSH + quad * 4 + tbase * 16;
    const unsigned short* cw = cs + n * TT;

    float cst[7], hf[7];
    #pragma unroll
    for (int tt = 0; tt < 7; ++tt) { cst[tt] = 0.0f; hf[tt] = 0.0f; }

    __syncthreads();

    int vcur = cw[(d && L > 0) ? (L - 1) : 0];   // pre-multiplied row offset
    int cur = 0;

    #pragma unroll 1
    for (int s = 0; s < mL; ++s) {
        bool valid = s < L;

        const short* hb = hs[cur];
        bf16x8 B0 = *(const bf16x8*)(hb + n * 64 + pa0 * 8);
        bf16x8 B1 = *(const bf16x8*)(hb + n * 64 + pa1 * 8);

        int sn = s + 1;                 // prefetch next char offset
        int pn = (sn < L) ? (d ? (L - 1 - sn) : sn) : 0;
        int vnxt = cw[pn];

        const int2* gp = (const int2*)(Gq + vcur);   // 8B per tile, L2
        short* hnb = hs[cur ^ 1];

        #pragma unroll
        for (int tt = 0; tt < 7; ++tt) {
            int2 gw = gp[tt * 4];       // tt*16 shorts = tt*4 int2
            f32x4 a;
            a[0] = bflo((unsigned)gw.x);  // gate i
            a[1] = bfhi((unsigned)gw.x);  // gate f
            a[2] = bflo((unsigned)gw.y);  // gate g
            a[3] = bfhi((unsigned)gw.y);  // gate o
            a = __builtin_amdgcn_mfma_f32_16x16x32_bf16(A0[tt], B0, a, 0, 0, 0);
            a = __builtin_amdgcn_mfma_f32_16x16x32_bf16(A1[tt], B1, a, 0, 0, 0);

            // exp2-domain gates (scales baked into G/W images)
            float ig = frcp(1.0f + fexp2(a[0]));
            float fg = frcp(1.0f + fexp2(a[1]));
            float tg = 1.0f - 2.0f * frcp(1.0f + fexp2(a[2]));
            float og = frcp(1.0f + fexp2(a[3]));
            float cn = fg * cst[tt] + ig * tg;
            float hn = og * (1.0f - 2.0f * frcp(1.0f + fexp2(cn * P2LOG2E)));

            int uu = u0 + 4 * tt;
            bool upd = valid && (uu < HH);
            cst[tt] = upd ? cn : cst[tt];
            hf[tt]  = upd ? hn : hf[tt];
            if (uu < HH) hnb[hidx[tt]] = f2bf(hf[tt]);  // frozen when invalid
        }

        vcur = vnxt;
        __syncthreads();
        cur ^= 1;
    }

    float* orow = out + (size_t)word * (2 * HH) + d * HH;
    #pragma unroll
    for (int tt = 0; tt < 7; ++tt) {
        int uu = u0 + 4 * tt;
        if (uu < HH) orow[uu] = hf[tt];   // tile 6 double-written: same value
    }
}

extern "C" void kernel_launch(void* const* d_in, const int* in_sizes, int n_in,
                              void* d_out, int out_size, void* d_ws, size_t ws_size,
                              hipStream_t stream) {
    const int*   chars = (const int*)d_in[0];
    const int*   lens  = (const int*)d_in[1];
    const float* emb   = (const float*)d_in[2];
    const float* Wih_f = (const float*)d_in[3];
    const float* Whh_f = (const float*)d_in[4];
    const float* bih_f = (const float*)d_in[5];
    const float* bhh_f = (const float*)d_in[6];
    const float* Wih_b = (const float*)d_in[7];
    const float* Whh_b = (const float*)d_in[8];
    const float* bih_b = (const float*)d_in[9];
    const float* bhh_b = (const float*)d_in[10];
    float* out = (float*)d_out;

    short* Gimg = (short*)d_ws;                 // 169600 B
    short* Wimg = Gimg + 2 * GSH;               //  53248 B
    int*   cnt  = (int*)(Wimg + 2 * WSH);       //  10752 B
    int*   perm = cnt + NB_H * 21;              // 131072 B   (total ~365 KB)

    k_prep<<<NB_G + NB_W + NB_H, 256, 0, stream>>>(emb, Wih_f, bih_f, bhh_f,
                                                   Wih_b, bih_b, bhh_b,
                                                   Whh_f, Whh_b, lens,
                                                   Gimg, Wimg, cnt);
    k_scat<<<NB_H, 256, 0, stream>>>(lens, cnt, perm);
    k_lstm<<<NBLK, 128, 0, stream>>>(chars, lens, perm, Gimg, Wimg, out);
}